// Round 7
// baseline (425.853 us; speedup 1.0000x reference)
//
#include <hip/hip_runtime.h>
#include <hip/hip_bf16.h>
#include <stdint.h>

typedef __bf16 bf16_t;
typedef bf16_t bf16x2 __attribute__((ext_vector_type(2)));
typedef bf16_t bf16x8 __attribute__((ext_vector_type(8)));
typedef float  f32x4  __attribute__((ext_vector_type(4)));
typedef float  f32x16 __attribute__((ext_vector_type(16)));
typedef unsigned uint2v __attribute__((ext_vector_type(2)));

#define NB_HEAD 16
#define DH      64
#define EMB     1024
#define BATCH   4
#define SEQ     2048
#define NTOK    (BATCH*SEQ)   // 8192

// scale * log2(e): folded into Q at projection time
#define QSCALE 0.1803368801111204f

// ---------------------------------------------------------------------------
// helpers
// ---------------------------------------------------------------------------
__device__ __forceinline__ void gload_lds16(const void* g, void* l) {
  __builtin_amdgcn_global_load_lds(
      (const __attribute__((address_space(1))) void*)g,
      (__attribute__((address_space(3))) void*)l, 16, 0, 0);
}

__device__ __forceinline__ uint32_t pkbf(float a, float b) {
  bf16x2 v = { (bf16_t)a, (bf16_t)b };     // fusable to v_cvt_pk_bf16_f32
  return __builtin_bit_cast(uint32_t, v);
}

__device__ __forceinline__ void cvt8_body(const float* __restrict__ in,
                                          bf16_t* __restrict__ out, int i) {
  const float4* p = reinterpret_cast<const float4*>(in) + (size_t)i * 2;
  float4 a = p[0], b = p[1];
  uint4 r;
  r.x = pkbf(a.x, a.y); r.y = pkbf(a.z, a.w);
  r.z = pkbf(b.x, b.y); r.w = pkbf(b.z, b.w);
  reinterpret_cast<uint4*>(out)[i] = r;
}

__device__ __forceinline__ void mkand_body(const uint8_t* __restrict__ m,
                                           uint16_t* __restrict__ out, int i) {
  uint2 v = reinterpret_cast<const uint2*>(m)[i];
  uint4 r;
  uint32_t lo = v.x, hi = v.y;
  uint16_t e[8];
#pragma unroll
  for (int j = 0; j < 4; j++) e[j]     = (uint16_t)(((lo >> (8 * j)) & 0xFF) - 1);
#pragma unroll
  for (int j = 0; j < 4; j++) e[4 + j] = (uint16_t)(((hi >> (8 * j)) & 0xFF) - 1);
  r.x = (uint32_t)e[0] | ((uint32_t)e[1] << 16);
  r.y = (uint32_t)e[2] | ((uint32_t)e[3] << 16);
  r.z = (uint32_t)e[4] | ((uint32_t)e[5] << 16);
  r.w = (uint32_t)e[6] | ((uint32_t)e[7] << 16);
  reinterpret_cast<uint4*>(out)[i] = r;
}

// ---------------------------------------------------------------------------
// prep: all f32->bf16 conversions (+ optional mask expansion) in ONE launch.
// ---------------------------------------------------------------------------
__global__ void __launch_bounds__(256)
prep(const float* __restrict__ hq, const float* __restrict__ hk,
     const float* __restrict__ hv, const float* __restrict__ Wq,
     const float* __restrict__ Wk, const float* __restrict__ Wv,
     const float* __restrict__ Wo,
     bf16_t* hq_b, bf16_t* hk_b, bf16_t* hv_b,
     bf16_t* Wq_b, bf16_t* Wk_b, bf16_t* Wv_b, bf16_t* Wo_b,
     const uint8_t* __restrict__ mask, uint16_t* __restrict__ mand) {
  const int bid = blockIdx.x;
  if (bid < 12288) {
    const int seg = bid >> 12;               // /4096
    const float* src = seg == 0 ? hq : seg == 1 ? hk : hv;
    bf16_t*      dst = seg == 0 ? hq_b : seg == 1 ? hk_b : hv_b;
    cvt8_body(src, dst, (bid & 4095) * 256 + (int)threadIdx.x);
  } else if (bid < 14336) {
    const int sb = bid - 12288;
    const int seg = sb >> 9;                 // /512
    const float* src = seg == 0 ? Wq : seg == 1 ? Wk : seg == 2 ? Wv : Wo;
    bf16_t*      dst = seg == 0 ? Wq_b : seg == 1 ? Wk_b : seg == 2 ? Wv_b : Wo_b;
    cvt8_body(src, dst, (sb & 511) * 256 + (int)threadIdx.x);
  } else {
    mkand_body(mask, mand, (bid - 14336) * 256 + (int)threadIdx.x);
  }
}

__global__ void __launch_bounds__(256)
mkand(const uint8_t* __restrict__ m, uint16_t* __restrict__ out) {
  mkand_body(m, out, blockIdx.x * 256 + (int)threadIdx.x);
}

// ---------------------------------------------------------------------------
// GEMM  C[M,N] = A[M,K] * Bw[N,K]^T, 128x128 tile, BK=64, double-buffered LDS
// (round-5 proven structure: stage at top, __syncthreads at bottom — race-free),
// XCD-swizzled block mapping.
// EPI 0: bf16 row-major, scaled by qscale  (Q) | EPI 1: Vt[b,h,d,s] (V)
// EPI 2: f32 + residual (out proj)             | EPI 3: Kh[b,h,s,d] (K)
// ---------------------------------------------------------------------------
#define BM 128
#define BN 128
#define BKT 64

template<int EPI>
__global__ void __launch_bounds__(256, 2)
gemm_bt(const bf16_t* __restrict__ A, const bf16_t* __restrict__ Bw,
        bf16_t* __restrict__ Cb, float* __restrict__ Cf,
        const float* __restrict__ resid, float qscale) {
  __shared__ bf16_t As[2][BM * BKT];
  __shared__ bf16_t Bs[2][BN * BKT];
  const int K = EMB, N = EMB;
  const int t    = threadIdx.x;
  const int lane = t & 63, w = t >> 6;
  const int wr = w >> 1, wc = w & 1;
  const int l15 = lane & 15, l4 = lane >> 4;

  // XCD swizzle: grid (8,64); give each XCD 8 contiguous row-stripes
  const int lin = blockIdx.x + 8 * blockIdx.y;
  const int nl  = (lin & 7) * 64 + (lin >> 3);
  const int rowBase = (nl >> 3) * BM, colBase = (nl & 7) * BN;

  f32x4 acc[4][4];
#pragma unroll
  for (int i = 0; i < 4; i++)
#pragma unroll
    for (int j = 0; j < 4; j++) acc[i][j] = f32x4{0.f, 0.f, 0.f, 0.f};

  const int lin16 = w * 1024 + lane * 16;

  // prologue: stage k0=0 into buf 0
#pragma unroll
  for (int i = 0; i < 4; ++i) {
    int off  = i * 4096 + lin16;
    int row  = off >> 7, colb = off & 127;
    gload_lds16((const char*)A  + (((size_t)(rowBase + row)) * K) * 2 + colb, (char*)As[0] + off);
    gload_lds16((const char*)Bw + (((size_t)(colBase + row)) * K) * 2 + colb, (char*)Bs[0] + off);
  }
  __syncthreads();

  int cur = 0;
  for (int k0 = 0; k0 < K; k0 += BKT) {
    if (k0 + BKT < K) {
      const int nb = cur ^ 1;
#pragma unroll
      for (int i = 0; i < 4; ++i) {
        int off  = i * 4096 + lin16;
        int row  = off >> 7, colb = off & 127;
        gload_lds16((const char*)A  + (((size_t)(rowBase + row)) * K + k0 + BKT) * 2 + colb, (char*)As[nb] + off);
        gload_lds16((const char*)Bw + (((size_t)(colBase + row)) * K + k0 + BKT) * 2 + colb, (char*)Bs[nb] + off);
      }
    }
#pragma unroll
    for (int kc = 0; kc < 2; ++kc) {
      bf16x8 af[4], bfb[4];
#pragma unroll
      for (int mi = 0; mi < 4; mi++)
        af[mi] = *reinterpret_cast<const bf16x8*>(
            &As[cur][(wr * 64 + mi * 16 + l15) * BKT + kc * 32 + l4 * 8]);
#pragma unroll
      for (int ni = 0; ni < 4; ni++)
        bfb[ni] = *reinterpret_cast<const bf16x8*>(
            &Bs[cur][(wc * 64 + ni * 16 + l15) * BKT + kc * 32 + l4 * 8]);
      __builtin_amdgcn_s_setprio(1);
#pragma unroll
      for (int mi = 0; mi < 4; mi++)
#pragma unroll
        for (int ni = 0; ni < 4; ni++)
          acc[mi][ni] = __builtin_amdgcn_mfma_f32_16x16x32_bf16(
              af[mi], bfb[ni], acc[mi][ni], 0, 0, 0);
      __builtin_amdgcn_s_setprio(0);
    }
    __syncthreads();   // drains vmcnt; protects both buffers (race-free)
    cur ^= 1;
  }

#pragma unroll
  for (int mi = 0; mi < 4; mi++) {
#pragma unroll
    for (int ni = 0; ni < 4; ni++) {
      const int m0 = rowBase + wr * 64 + mi * 16 + l4 * 4;
      const int n  = colBase + wc * 64 + ni * 16 + l15;
      if (EPI == 1) {
        size_t base = ((size_t)((m0 >> 11) * 1024 + n)) * 2048 + (m0 & 2047);
        uint2 st;
        st.x = pkbf(acc[mi][ni][0], acc[mi][ni][1]);
        st.y = pkbf(acc[mi][ni][2], acc[mi][ni][3]);
        *reinterpret_cast<uint2*>(Cb + base) = st;
      } else {
#pragma unroll
        for (int r = 0; r < 4; r++) {
          int m = m0 + r;
          float v = acc[mi][ni][r];
          if (EPI == 0) {
            Cb[(size_t)m * N + n] = (bf16_t)(v * qscale);
          } else if (EPI == 3) {
            Cb[(((size_t)((m >> 11) * 16 + (n >> 6))) * 2048 + (m & 2047)) * 64 + (n & 63)] = (bf16_t)v;
          } else {
            Cf[(size_t)m * N + n] = v + resid[(size_t)m * N + n];
          }
        }
      }
    }
  }
}

// ---------------------------------------------------------------------------
// Flash attention, swapped-operand 32x32x16, POST-softmax masking, no online
// max (Q pre-scaled by 0.125*log2e; P = exp2(acc)); denominator = VALU sum of
// unmasked P. Round-5 proven sync structure (stage at top, __syncthreads at
// bottom). Masks for the WHOLE tile prefetched at loop top, issued BEFORE the
// stage loads (in-order vmcnt retirement: consuming them never drains stage).
// 512 thr = 8 waves x 32 q-rows; KVBLK=128 (two 64-k halves per barrier).
// ---------------------------------------------------------------------------
#define KVB 128

__global__ void __launch_bounds__(512, 4)
attn32(const bf16_t* __restrict__ Qb, const bf16_t* __restrict__ Kh,
       const bf16_t* __restrict__ Vt, const uint16_t* __restrict__ Mand,
       bf16_t* __restrict__ ctx) {
  __shared__ __align__(16) bf16_t Ks[2][KVB * 64];   // 16 KB each buf
  __shared__ __align__(16) bf16_t Vs[2][64 * KVB];   // 16 KB each buf

  const int t = threadIdx.x, lane = t & 63, wid = t >> 6;
  const int q = lane & 31, hi = lane >> 5;

  // XCD swizzle: 512 blocks; each XCD gets 8 contiguous (b,h) K/V sets
  const int lin = blockIdx.x + 8 * (blockIdx.y + 16 * blockIdx.z);
  const int nl  = (lin & 7) * 64 + (lin >> 3);
  const int bx = nl & 7, h = (nl >> 3) & 15, b = nl >> 7;

  const int q0 = bx * 256 + wid * 32;
  const int qrow = b * SEQ + q0 + q;

  // staging geometry (pre-swizzled source cols, linear LDS dest)
  const int srow8  = t >> 3;                            // K: 8 thr per 128B row
  const int scol8  = ((t & 7) ^ ((t >> 3) & 7)) * 16;
  const int srow16 = t >> 4;                            // V: 16 thr per 256B row
  const int scol16 = (((t & 15) ^ ((t >> 4) & 7)) & 15) * 16;
  const char* kg = (const char*)(Kh + ((size_t)(b * NB_HEAD + h)) * SEQ * DH);
  const char* vg = (const char*)(Vt + ((size_t)(b * NB_HEAD + h)) * DH * SEQ);

  // Q fragments (B operand), pre-scaled
  const bf16_t* qp = Qb + (size_t)qrow * EMB + h * DH + hi * 8;
  bf16x8 qf[4];
#pragma unroll
  for (int d = 0; d < 4; d++) qf[d] = *reinterpret_cast<const bf16x8*>(qp + d * 16);

  f32x16 o0 = {0}, o1 = {0};
  float lrun = 0.f;
  const uint16_t* mbase = Mand + (size_t)qrow * SEQ;
  const int qx = (q & 7) << 4;   // swizzled read col (bits 4-6 only)

  // prologue: stage tile 0 into buf 0
  gload_lds16(kg + (size_t)srow8 * 128 + scol8,                 (char*)Ks[0] + t * 16);
  gload_lds16(kg + (size_t)(64 + srow8) * 128 + scol8,          (char*)Ks[0] + 8192 + t * 16);
  gload_lds16(vg + (size_t)srow16 * 4096 + scol16,              (char*)Vs[0] + t * 16);
  gload_lds16(vg + (size_t)(32 + srow16) * 4096 + scol16,       (char*)Vs[0] + 8192 + t * 16);
  __syncthreads();

  int cur = 0;
#pragma unroll 1
  for (int kb = 0; kb < SEQ; kb += KVB) {
    // ---- mask prefetch for the whole tile, ISSUED FIRST (in-order vmcnt:
    //      consuming these never forces the stage loads to drain) ----
    uint4 mv[8];
#pragma unroll
    for (int j = 0; j < 8; j++)
      mv[j] = *reinterpret_cast<const uint4*>(mbase + kb + 16 * j + 8 * hi);

    // ---- issue next tile's staging (lands by the bottom barrier) ----
    if (kb + KVB < SEQ) {
      const int nb = cur ^ 1;
      const size_t kO = (size_t)(kb + KVB) * 128;
      const size_t vO = (size_t)(kb + KVB) * 2;
      gload_lds16(kg + kO + (size_t)srow8 * 128 + scol8,           (char*)Ks[nb] + t * 16);
      gload_lds16(kg + kO + (size_t)(64 + srow8) * 128 + scol8,    (char*)Ks[nb] + 8192 + t * 16);
      gload_lds16(vg + vO + (size_t)srow16 * 4096 + scol16,        (char*)Vs[nb] + t * 16);
      gload_lds16(vg + vO + (size_t)(32 + srow16) * 4096 + scol16, (char*)Vs[nb] + 8192 + t * 16);
    }

#pragma unroll
    for (int hh = 0; hh < 2; hh++) {
      // ---- QK^T (swapped) from LDS half hh ----
      const char* kls = (const char*)Ks[cur] + hh * 8192;
      f32x16 p0 = {0}, p1 = {0};
      __builtin_amdgcn_s_setprio(1);
#pragma unroll
      for (int dsl = 0; dsl < 4; dsl++) {
        const int cb = (dsl * 32 + hi * 16) ^ qx;
        bf16x8 kf0 = *reinterpret_cast<const bf16x8*>(kls + q * 128 + cb);
        bf16x8 kf1 = *reinterpret_cast<const bf16x8*>(kls + (32 + q) * 128 + cb);
        p0 = __builtin_amdgcn_mfma_f32_32x32x16_bf16(kf0, qf[dsl], p0, 0, 0, 0);
        p1 = __builtin_amdgcn_mfma_f32_32x32x16_bf16(kf1, qf[dsl], p1, 0, 0, 0);
      }
      __builtin_amdgcn_s_setprio(0);

      const char* vls = (const char*)Vs[cur];

      // exp p0, then ks0/ks1 (consume p0), exp p1, ks2/ks3 — VALU/MFMA overlap
      float ps = 0.f;
#pragma unroll
      for (int i = 0; i < 16; i++) { p0[i] = __builtin_amdgcn_exp2f(p0[i]); ps += p0[i]; }

#pragma unroll
      for (int half = 0; half < 2; half++) {
        if (half == 1) {
#pragma unroll
          for (int i = 0; i < 16; i++) { p1[i] = __builtin_amdgcn_exp2f(p1[i]); ps += p1[i]; }
        }
        const f32x16& ph = half ? p1 : p0;
#pragma unroll
        for (int kss = 0; kss < 2; kss++) {
          const int ks = half * 2 + kss;
          const int s8 = kss * 8;
          uint32_t a0 = pkbf(ph[s8+0], ph[s8+1]), a1 = pkbf(ph[s8+2], ph[s8+3]);
          uint32_t a2 = pkbf(ph[s8+4], ph[s8+5]), a3 = pkbf(ph[s8+6], ph[s8+7]);
          uint2v s02 = __builtin_amdgcn_permlane32_swap(a0, a2, false, false);
          uint2v s13 = __builtin_amdgcn_permlane32_swap(a1, a3, false, false);
          uint4 fr;
          fr.x = s02[0]; fr.y = s13[0]; fr.z = s02[1]; fr.w = s13[1];
          const uint4 m = mv[hh * 4 + ks];
          fr.x &= m.x; fr.y &= m.y; fr.z &= m.z; fr.w &= m.w;
          bf16x8 pa = __builtin_bit_cast(bf16x8, fr);
          const int cbv = (hh * 128 + ks * 32 + hi * 16) ^ qx;
          bf16x8 vf0 = *reinterpret_cast<const bf16x8*>(vls + q * 256 + cbv);
          bf16x8 vf1 = *reinterpret_cast<const bf16x8*>(vls + (32 + q) * 256 + cbv);
          __builtin_amdgcn_s_setprio(1);
          o0 = __builtin_amdgcn_mfma_f32_32x32x16_bf16(vf0, pa, o0, 0, 0, 0);
          o1 = __builtin_amdgcn_mfma_f32_32x32x16_bf16(vf1, pa, o1, 0, 0, 0);
          __builtin_amdgcn_s_setprio(0);
        }
      }
      // denominator: UNMASKED sum over this half's 32 k
      ps += __shfl_xor(ps, 32);
      lrun += ps;
    }

    __syncthreads();   // drains vmcnt (next-tile stage) + protects buffers
    cur ^= 1;
  }

  // ---- epilogue ----
  float inv = 1.0f / lrun;
  bf16_t* cp = ctx + (size_t)qrow * EMB + h * DH;
#pragma unroll
  for (int g = 0; g < 4; g++) {
    uint2 st;
    st.x = pkbf(o0[4*g+0] * inv, o0[4*g+1] * inv);
    st.y = pkbf(o0[4*g+2] * inv, o0[4*g+3] * inv);
    *reinterpret_cast<uint2*>(cp + 8 * g + 4 * hi) = st;
    st.x = pkbf(o1[4*g+0] * inv, o1[4*g+1] * inv);
    st.y = pkbf(o1[4*g+2] * inv, o1[4*g+3] * inv);
    *reinterpret_cast<uint2*>(cp + 32 + 8 * g + 4 * hi) = st;
  }
}

// ---------------------------------------------------------------------------
// launcher
// ---------------------------------------------------------------------------
extern "C" void kernel_launch(void* const* d_in, const int* in_sizes, int n_in,
                              void* d_out, int out_size, void* d_ws, size_t ws_size,
                              hipStream_t stream) {
  const float*   hq   = (const float*)d_in[0];
  const float*   hk   = (const float*)d_in[1];
  const float*   hv   = (const float*)d_in[2];
  const uint8_t* mask = (const uint8_t*)d_in[3];
  const float*   Wq   = (const float*)d_in[4];
  const float*   Wk   = (const float*)d_in[5];
  const float*   Wv   = (const float*)d_in[6];
  const float*   Wo   = (const float*)d_in[7];
  float* out = (float*)d_out;

  char* ws = (char*)d_ws;
  const size_t SZ_H = (size_t)NTOK * EMB * 2;        // 16 MiB
  const size_t SZ_W = (size_t)EMB * EMB * 2;         // 2 MiB
  bf16_t* hq_b = (bf16_t*)(ws + 0 * SZ_H);
  bf16_t* hk_b = (bf16_t*)(ws + 1 * SZ_H);
  bf16_t* hv_b = (bf16_t*)(ws + 2 * SZ_H);
  bf16_t* Qb   = (bf16_t*)(ws + 3 * SZ_H);
  bf16_t* Kh   = (bf16_t*)(ws + 4 * SZ_H);
  bf16_t* Vt   = (bf16_t*)(ws + 5 * SZ_H);
  bf16_t* ctx  = (bf16_t*)(ws + 6 * SZ_H);
  bf16_t* Wq_b = (bf16_t*)(ws + 7 * SZ_H + 0 * SZ_W);
  bf16_t* Wk_b = (bf16_t*)(ws + 7 * SZ_H + 1 * SZ_W);
  bf16_t* Wv_b = (bf16_t*)(ws + 7 * SZ_H + 2 * SZ_W);
  bf16_t* Wo_b = (bf16_t*)(ws + 7 * SZ_H + 3 * SZ_W);

  const size_t MAND_OFF = 7 * SZ_H + 4 * SZ_W;                 // 120 MiB
  const size_t MAND_SZ  = (size_t)BATCH * SEQ * SEQ * 2;       // 32 MiB
  const bool bigws = ws_size >= MAND_OFF + MAND_SZ;
  uint16_t* Mand = bigws ? (uint16_t*)(ws + MAND_OFF) : (uint16_t*)ws;

  prep<<<bigws ? 22528 : 14336, 256, 0, stream>>>(
      hq, hk, hv, Wq, Wk, Wv, Wo,
      hq_b, hk_b, hv_b, Wq_b, Wk_b, Wv_b, Wo_b, mask, Mand);

  dim3 ggrid(EMB / BN, NTOK / BM);  // (8, 64)
  gemm_bt<0><<<ggrid, 256, 0, stream>>>(hq_b, Wq_b, Qb, nullptr, nullptr, QSCALE);
  gemm_bt<3><<<ggrid, 256, 0, stream>>>(hk_b, Wk_b, Kh, nullptr, nullptr, 1.0f);
  gemm_bt<1><<<ggrid, 256, 0, stream>>>(hv_b, Wv_b, Vt, nullptr, nullptr, 1.0f);

  if (!bigws) mkand<<<8192, 256, 0, stream>>>(mask, Mand);

  attn32<<<dim3(SEQ / 256, NB_HEAD, BATCH), 512, 0, stream>>>(Qb, Kh, Vt, Mand, ctx);

  gemm_bt<2><<<ggrid, 256, 0, stream>>>(ctx, Wo_b, nullptr, out, hq, 1.0f);
}

// Round 8
// 398.324 us; speedup vs baseline: 1.0691x; 1.0691x over previous
//
#include <hip/hip_runtime.h>
#include <hip/hip_bf16.h>
#include <stdint.h>

typedef __bf16 bf16_t;
typedef bf16_t bf16x2 __attribute__((ext_vector_type(2)));
typedef bf16_t bf16x8 __attribute__((ext_vector_type(8)));
typedef float  f32x4  __attribute__((ext_vector_type(4)));
typedef float  f32x16 __attribute__((ext_vector_type(16)));
typedef unsigned uint2v __attribute__((ext_vector_type(2)));

#define NB_HEAD 16
#define DH      64
#define EMB     1024
#define BATCH   4
#define SEQ     2048
#define NTOK    (BATCH*SEQ)   // 8192

// scale * log2(e): folded into Q at projection time
#define QSCALE 0.1803368801111204f

// ---------------------------------------------------------------------------
// helpers
// ---------------------------------------------------------------------------
__device__ __forceinline__ void gload_lds16(const void* g, void* l) {
  __builtin_amdgcn_global_load_lds(
      (const __attribute__((address_space(1))) void*)g,
      (__attribute__((address_space(3))) void*)l, 16, 0, 0);
}

__device__ __forceinline__ uint32_t pkbf(float a, float b) {
  bf16x2 v = { (bf16_t)a, (bf16_t)b };     // fusable to v_cvt_pk_bf16_f32
  return __builtin_bit_cast(uint32_t, v);
}

__device__ __forceinline__ void cvt8_body(const float* __restrict__ in,
                                          bf16_t* __restrict__ out, int i) {
  const float4* p = reinterpret_cast<const float4*>(in) + (size_t)i * 2;
  float4 a = p[0], b = p[1];
  uint4 r;
  r.x = pkbf(a.x, a.y); r.y = pkbf(a.z, a.w);
  r.z = pkbf(b.x, b.y); r.w = pkbf(b.z, b.w);
  reinterpret_cast<uint4*>(out)[i] = r;
}

__device__ __forceinline__ void mkand_body(const uint8_t* __restrict__ m,
                                           uint16_t* __restrict__ out, int i) {
  uint2 v = reinterpret_cast<const uint2*>(m)[i];
  uint4 r;
  uint32_t lo = v.x, hi = v.y;
  uint16_t e[8];
#pragma unroll
  for (int j = 0; j < 4; j++) e[j]     = (uint16_t)(((lo >> (8 * j)) & 0xFF) - 1);
#pragma unroll
  for (int j = 0; j < 4; j++) e[4 + j] = (uint16_t)(((hi >> (8 * j)) & 0xFF) - 1);
  r.x = (uint32_t)e[0] | ((uint32_t)e[1] << 16);
  r.y = (uint32_t)e[2] | ((uint32_t)e[3] << 16);
  r.z = (uint32_t)e[4] | ((uint32_t)e[5] << 16);
  r.w = (uint32_t)e[6] | ((uint32_t)e[7] << 16);
  reinterpret_cast<uint4*>(out)[i] = r;
}

// ---------------------------------------------------------------------------
// prep: all f32->bf16 conversions (+ optional mask expansion) in ONE launch.
// ---------------------------------------------------------------------------
__global__ void __launch_bounds__(256)
prep(const float* __restrict__ hq, const float* __restrict__ hk,
     const float* __restrict__ hv, const float* __restrict__ Wq,
     const float* __restrict__ Wk, const float* __restrict__ Wv,
     const float* __restrict__ Wo,
     bf16_t* hq_b, bf16_t* hk_b, bf16_t* hv_b,
     bf16_t* Wq_b, bf16_t* Wk_b, bf16_t* Wv_b, bf16_t* Wo_b,
     const uint8_t* __restrict__ mask, uint16_t* __restrict__ mand) {
  const int bid = blockIdx.x;
  if (bid < 12288) {
    const int seg = bid >> 12;               // /4096
    const float* src = seg == 0 ? hq : seg == 1 ? hk : hv;
    bf16_t*      dst = seg == 0 ? hq_b : seg == 1 ? hk_b : hv_b;
    cvt8_body(src, dst, (bid & 4095) * 256 + (int)threadIdx.x);
  } else if (bid < 14336) {
    const int sb = bid - 12288;
    const int seg = sb >> 9;                 // /512
    const float* src = seg == 0 ? Wq : seg == 1 ? Wk : seg == 2 ? Wv : Wo;
    bf16_t*      dst = seg == 0 ? Wq_b : seg == 1 ? Wk_b : seg == 2 ? Wv_b : Wo_b;
    cvt8_body(src, dst, (sb & 511) * 256 + (int)threadIdx.x);
  } else {
    mkand_body(mask, mand, (bid - 14336) * 256 + (int)threadIdx.x);
  }
}

__global__ void __launch_bounds__(256)
mkand(const uint8_t* __restrict__ m, uint16_t* __restrict__ out) {
  mkand_body(m, out, blockIdx.x * 256 + (int)threadIdx.x);
}

// ---------------------------------------------------------------------------
// GEMM  C[M,N] = A[M,K] * Bw[N,K]^T, 128x128 tile, BK=64, double-buffered LDS
// (proven structure: stage at top, __syncthreads at bottom — race-free),
// XCD-swizzled block mapping.
// EPI 0: bf16 row-major, scaled by qscale  (Q) | EPI 1: Vt[b,h,d,s] (V)
// EPI 2: f32 + residual (out proj)             | EPI 3: Kh[b,h,s,d] (K)
// ---------------------------------------------------------------------------
#define BM 128
#define BN 128
#define BKT 64

template<int EPI>
__global__ void __launch_bounds__(256, 2)
gemm_bt(const bf16_t* __restrict__ A, const bf16_t* __restrict__ Bw,
        bf16_t* __restrict__ Cb, float* __restrict__ Cf,
        const float* __restrict__ resid, float qscale) {
  __shared__ bf16_t As[2][BM * BKT];
  __shared__ bf16_t Bs[2][BN * BKT];
  const int K = EMB, N = EMB;
  const int t    = threadIdx.x;
  const int lane = t & 63, w = t >> 6;
  const int wr = w >> 1, wc = w & 1;
  const int l15 = lane & 15, l4 = lane >> 4;

  // XCD swizzle: grid (8,64); give each XCD 8 contiguous row-stripes
  const int lin = blockIdx.x + 8 * blockIdx.y;
  const int nl  = (lin & 7) * 64 + (lin >> 3);
  const int rowBase = (nl >> 3) * BM, colBase = (nl & 7) * BN;

  f32x4 acc[4][4];
#pragma unroll
  for (int i = 0; i < 4; i++)
#pragma unroll
    for (int j = 0; j < 4; j++) acc[i][j] = f32x4{0.f, 0.f, 0.f, 0.f};

  const int lin16 = w * 1024 + lane * 16;

  // prologue: stage k0=0 into buf 0
#pragma unroll
  for (int i = 0; i < 4; ++i) {
    int off  = i * 4096 + lin16;
    int row  = off >> 7, colb = off & 127;
    gload_lds16((const char*)A  + (((size_t)(rowBase + row)) * K) * 2 + colb, (char*)As[0] + off);
    gload_lds16((const char*)Bw + (((size_t)(colBase + row)) * K) * 2 + colb, (char*)Bs[0] + off);
  }
  __syncthreads();

  int cur = 0;
  for (int k0 = 0; k0 < K; k0 += BKT) {
    if (k0 + BKT < K) {
      const int nb = cur ^ 1;
#pragma unroll
      for (int i = 0; i < 4; ++i) {
        int off  = i * 4096 + lin16;
        int row  = off >> 7, colb = off & 127;
        gload_lds16((const char*)A  + (((size_t)(rowBase + row)) * K + k0 + BKT) * 2 + colb, (char*)As[nb] + off);
        gload_lds16((const char*)Bw + (((size_t)(colBase + row)) * K + k0 + BKT) * 2 + colb, (char*)Bs[nb] + off);
      }
    }
#pragma unroll
    for (int kc = 0; kc < 2; ++kc) {
      bf16x8 af[4], bfb[4];
#pragma unroll
      for (int mi = 0; mi < 4; mi++)
        af[mi] = *reinterpret_cast<const bf16x8*>(
            &As[cur][(wr * 64 + mi * 16 + l15) * BKT + kc * 32 + l4 * 8]);
#pragma unroll
      for (int ni = 0; ni < 4; ni++)
        bfb[ni] = *reinterpret_cast<const bf16x8*>(
            &Bs[cur][(wc * 64 + ni * 16 + l15) * BKT + kc * 32 + l4 * 8]);
      __builtin_amdgcn_s_setprio(1);
#pragma unroll
      for (int mi = 0; mi < 4; mi++)
#pragma unroll
        for (int ni = 0; ni < 4; ni++)
          acc[mi][ni] = __builtin_amdgcn_mfma_f32_16x16x32_bf16(
              af[mi], bfb[ni], acc[mi][ni], 0, 0, 0);
      __builtin_amdgcn_s_setprio(0);
    }
    __syncthreads();   // drains vmcnt; protects both buffers (race-free)
    cur ^= 1;
  }

#pragma unroll
  for (int mi = 0; mi < 4; mi++) {
#pragma unroll
    for (int ni = 0; ni < 4; ni++) {
      const int m0 = rowBase + wr * 64 + mi * 16 + l4 * 4;
      const int n  = colBase + wc * 64 + ni * 16 + l15;
      if (EPI == 1) {
        size_t base = ((size_t)((m0 >> 11) * 1024 + n)) * 2048 + (m0 & 2047);
        uint2 st;
        st.x = pkbf(acc[mi][ni][0], acc[mi][ni][1]);
        st.y = pkbf(acc[mi][ni][2], acc[mi][ni][3]);
        *reinterpret_cast<uint2*>(Cb + base) = st;
      } else {
#pragma unroll
        for (int r = 0; r < 4; r++) {
          int m = m0 + r;
          float v = acc[mi][ni][r];
          if (EPI == 0) {
            Cb[(size_t)m * N + n] = (bf16_t)(v * qscale);
          } else if (EPI == 3) {
            Cb[(((size_t)((m >> 11) * 16 + (n >> 6))) * 2048 + (m & 2047)) * 64 + (n & 63)] = (bf16_t)v;
          } else {
            Cf[(size_t)m * N + n] = v + resid[(size_t)m * N + n];
          }
        }
      }
    }
  }
}

// ---------------------------------------------------------------------------
// Flash attention, swapped-operand 32x32x16, POST-softmax masking, no online
// max (Q pre-scaled by 0.125*log2e; P = exp2(acc)); denominator = VALU sum of
// unmasked P (ps). R5's proven sync structure (stage at top, __syncthreads at
// bottom); masks loaded inside each hh AFTER QK^T (short live range — R6/R7's
// hoisting caused per-iter scratch spills, 576 MB WRITE).
// 512 thr = 8 waves x 32 q-rows; KVBLK=128 (two 64-k halves per barrier).
// ---------------------------------------------------------------------------
#define KVB 128

__global__ void __launch_bounds__(512, 4)
attn32(const bf16_t* __restrict__ Qb, const bf16_t* __restrict__ Kh,
       const bf16_t* __restrict__ Vt, const uint16_t* __restrict__ Mand,
       bf16_t* __restrict__ ctx) {
  __shared__ __align__(16) bf16_t Ks[2][KVB * 64];   // 16 KB each buf
  __shared__ __align__(16) bf16_t Vs[2][64 * KVB];   // 16 KB each buf

  const int t = threadIdx.x, lane = t & 63, wid = t >> 6;
  const int q = lane & 31, hi = lane >> 5;

  // XCD swizzle: 512 blocks; each XCD gets 8 contiguous (b,h) K/V sets
  const int lin = blockIdx.x + 8 * (blockIdx.y + 16 * blockIdx.z);
  const int nl  = (lin & 7) * 64 + (lin >> 3);
  const int bx = nl & 7, h = (nl >> 3) & 15, b = nl >> 7;

  const int q0 = bx * 256 + wid * 32;
  const int qrow = b * SEQ + q0 + q;

  // staging geometry (pre-swizzled source cols, linear LDS dest)
  const int srow8  = t >> 3;                            // K: 8 thr per 128B row
  const int scol8  = ((t & 7) ^ ((t >> 3) & 7)) * 16;
  const int srow16 = t >> 4;                            // V: 16 thr per 256B row
  const int scol16 = (((t & 15) ^ ((t >> 4) & 7)) & 15) * 16;
  const char* kg = (const char*)(Kh + ((size_t)(b * NB_HEAD + h)) * SEQ * DH);
  const char* vg = (const char*)(Vt + ((size_t)(b * NB_HEAD + h)) * DH * SEQ);

  // Q fragments (B operand), pre-scaled
  const bf16_t* qp = Qb + (size_t)qrow * EMB + h * DH + hi * 8;
  bf16x8 qf[4];
#pragma unroll
  for (int d = 0; d < 4; d++) qf[d] = *reinterpret_cast<const bf16x8*>(qp + d * 16);

  f32x16 o0 = {0}, o1 = {0};
  float lrun = 0.f;
  const uint16_t* mbase = Mand + (size_t)qrow * SEQ;
  const int qx = (q & 7) << 4;   // swizzled read col (bits 4-6 only)

  // prologue: stage tile 0 into buf 0
  gload_lds16(kg + (size_t)srow8 * 128 + scol8,                 (char*)Ks[0] + t * 16);
  gload_lds16(kg + (size_t)(64 + srow8) * 128 + scol8,          (char*)Ks[0] + 8192 + t * 16);
  gload_lds16(vg + (size_t)srow16 * 4096 + scol16,              (char*)Vs[0] + t * 16);
  gload_lds16(vg + (size_t)(32 + srow16) * 4096 + scol16,       (char*)Vs[0] + 8192 + t * 16);
  __syncthreads();

  int cur = 0;
#pragma unroll 1
  for (int kb = 0; kb < SEQ; kb += KVB) {
    // issue next tile's staging (overlaps with this tile's compute)
    if (kb + KVB < SEQ) {
      const int nb = cur ^ 1;
      const size_t kO = (size_t)(kb + KVB) * 128;
      const size_t vO = (size_t)(kb + KVB) * 2;
      gload_lds16(kg + kO + (size_t)srow8 * 128 + scol8,           (char*)Ks[nb] + t * 16);
      gload_lds16(kg + kO + (size_t)(64 + srow8) * 128 + scol8,    (char*)Ks[nb] + 8192 + t * 16);
      gload_lds16(vg + vO + (size_t)srow16 * 4096 + scol16,        (char*)Vs[nb] + t * 16);
      gload_lds16(vg + vO + (size_t)(32 + srow16) * 4096 + scol16, (char*)Vs[nb] + 8192 + t * 16);
    }

#pragma unroll
    for (int hh = 0; hh < 2; hh++) {
      // ---- QK^T (swapped) from LDS half hh ----
      const char* kls = (const char*)Ks[cur] + hh * 8192;
      f32x16 p0 = {0}, p1 = {0};
      __builtin_amdgcn_s_setprio(1);
#pragma unroll
      for (int dsl = 0; dsl < 4; dsl++) {
        const int cb = (dsl * 32 + hi * 16) ^ qx;
        bf16x8 kf0 = *reinterpret_cast<const bf16x8*>(kls + q * 128 + cb);
        bf16x8 kf1 = *reinterpret_cast<const bf16x8*>(kls + (32 + q) * 128 + cb);
        p0 = __builtin_amdgcn_mfma_f32_32x32x16_bf16(kf0, qf[dsl], p0, 0, 0, 0);
        p1 = __builtin_amdgcn_mfma_f32_32x32x16_bf16(kf1, qf[dsl], p1, 0, 0, 0);
      }
      __builtin_amdgcn_s_setprio(0);

      // mask loads AFTER QK^T (short live range; latency hidden under exp)
      uint4 mv[4];
#pragma unroll
      for (int ks = 0; ks < 4; ks++)
        mv[ks] = *reinterpret_cast<const uint4*>(mbase + kb + 64 * hh + 16 * ks + 8 * hi);

      const char* vls = (const char*)Vs[cur];

      // exp p0, then ks0/ks1 (consume p0), exp p1, ks2/ks3 — VALU/MFMA overlap
      float ps = 0.f;
#pragma unroll
      for (int i = 0; i < 16; i++) { p0[i] = __builtin_amdgcn_exp2f(p0[i]); ps += p0[i]; }

#pragma unroll
      for (int half = 0; half < 2; half++) {
        if (half == 1) {
#pragma unroll
          for (int i = 0; i < 16; i++) { p1[i] = __builtin_amdgcn_exp2f(p1[i]); ps += p1[i]; }
        }
        const f32x16& ph = half ? p1 : p0;
#pragma unroll
        for (int kss = 0; kss < 2; kss++) {
          const int ks = half * 2 + kss;
          const int s8 = kss * 8;
          uint32_t a0 = pkbf(ph[s8+0], ph[s8+1]), a1 = pkbf(ph[s8+2], ph[s8+3]);
          uint32_t a2 = pkbf(ph[s8+4], ph[s8+5]), a3 = pkbf(ph[s8+6], ph[s8+7]);
          uint2v s02 = __builtin_amdgcn_permlane32_swap(a0, a2, false, false);
          uint2v s13 = __builtin_amdgcn_permlane32_swap(a1, a3, false, false);
          uint4 fr;
          fr.x = s02[0]; fr.y = s13[0]; fr.z = s02[1]; fr.w = s13[1];
          fr.x &= mv[ks].x; fr.y &= mv[ks].y; fr.z &= mv[ks].z; fr.w &= mv[ks].w;
          bf16x8 pa = __builtin_bit_cast(bf16x8, fr);
          const int cbv = (hh * 128 + ks * 32 + hi * 16) ^ qx;
          bf16x8 vf0 = *reinterpret_cast<const bf16x8*>(vls + q * 256 + cbv);
          bf16x8 vf1 = *reinterpret_cast<const bf16x8*>(vls + (32 + q) * 256 + cbv);
          __builtin_amdgcn_s_setprio(1);
          o0 = __builtin_amdgcn_mfma_f32_32x32x16_bf16(vf0, pa, o0, 0, 0, 0);
          o1 = __builtin_amdgcn_mfma_f32_32x32x16_bf16(vf1, pa, o1, 0, 0, 0);
          __builtin_amdgcn_s_setprio(0);
        }
      }
      // denominator: UNMASKED sum over this half's 32 k
      ps += __shfl_xor(ps, 32);
      lrun += ps;
    }

    __syncthreads();   // drains vmcnt (next-tile stage) + protects buffers
    cur ^= 1;
  }

  // ---- epilogue ----
  float inv = 1.0f / lrun;
  bf16_t* cp = ctx + (size_t)qrow * EMB + h * DH;
#pragma unroll
  for (int g = 0; g < 4; g++) {
    uint2 st;
    st.x = pkbf(o0[4*g+0] * inv, o0[4*g+1] * inv);
    st.y = pkbf(o0[4*g+2] * inv, o0[4*g+3] * inv);
    *reinterpret_cast<uint2*>(cp + 8 * g + 4 * hi) = st;
    st.x = pkbf(o1[4*g+0] * inv, o1[4*g+1] * inv);
    st.y = pkbf(o1[4*g+2] * inv, o1[4*g+3] * inv);
    *reinterpret_cast<uint2*>(cp + 32 + 8 * g + 4 * hi) = st;
  }
}

// ---------------------------------------------------------------------------
// launcher
// ---------------------------------------------------------------------------
extern "C" void kernel_launch(void* const* d_in, const int* in_sizes, int n_in,
                              void* d_out, int out_size, void* d_ws, size_t ws_size,
                              hipStream_t stream) {
  const float*   hq   = (const float*)d_in[0];
  const float*   hk   = (const float*)d_in[1];
  const float*   hv   = (const float*)d_in[2];
  const uint8_t* mask = (const uint8_t*)d_in[3];
  const float*   Wq   = (const float*)d_in[4];
  const float*   Wk   = (const float*)d_in[5];
  const float*   Wv   = (const float*)d_in[6];
  const float*   Wo   = (const float*)d_in[7];
  float* out = (float*)d_out;

  char* ws = (char*)d_ws;
  const size_t SZ_H = (size_t)NTOK * EMB * 2;        // 16 MiB
  const size_t SZ_W = (size_t)EMB * EMB * 2;         // 2 MiB
  bf16_t* hq_b = (bf16_t*)(ws + 0 * SZ_H);
  bf16_t* hk_b = (bf16_t*)(ws + 1 * SZ_H);
  bf16_t* hv_b = (bf16_t*)(ws + 2 * SZ_H);
  bf16_t* Qb   = (bf16_t*)(ws + 3 * SZ_H);
  bf16_t* Kh   = (bf16_t*)(ws + 4 * SZ_H);
  bf16_t* Vt   = (bf16_t*)(ws + 5 * SZ_H);
  bf16_t* ctx  = (bf16_t*)(ws + 6 * SZ_H);
  bf16_t* Wq_b = (bf16_t*)(ws + 7 * SZ_H + 0 * SZ_W);
  bf16_t* Wk_b = (bf16_t*)(ws + 7 * SZ_H + 1 * SZ_W);
  bf16_t* Wv_b = (bf16_t*)(ws + 7 * SZ_H + 2 * SZ_W);
  bf16_t* Wo_b = (bf16_t*)(ws + 7 * SZ_H + 3 * SZ_W);

  const size_t MAND_OFF = 7 * SZ_H + 4 * SZ_W;                 // 120 MiB
  const size_t MAND_SZ  = (size_t)BATCH * SEQ * SEQ * 2;       // 32 MiB
  const bool bigws = ws_size >= MAND_OFF + MAND_SZ;
  uint16_t* Mand = bigws ? (uint16_t*)(ws + MAND_OFF) : (uint16_t*)ws;

  prep<<<bigws ? 22528 : 14336, 256, 0, stream>>>(
      hq, hk, hv, Wq, Wk, Wv, Wo,
      hq_b, hk_b, hv_b, Wq_b, Wk_b, Wv_b, Wo_b, mask, Mand);

  dim3 ggrid(EMB / BN, NTOK / BM);  // (8, 64)
  gemm_bt<0><<<ggrid, 256, 0, stream>>>(hq_b, Wq_b, Qb, nullptr, nullptr, QSCALE);
  gemm_bt<3><<<ggrid, 256, 0, stream>>>(hk_b, Wk_b, Kh, nullptr, nullptr, 1.0f);
  gemm_bt<1><<<ggrid, 256, 0, stream>>>(hv_b, Wv_b, Vt, nullptr, nullptr, 1.0f);

  if (!bigws) mkand<<<8192, 256, 0, stream>>>(mask, Mand);

  attn32<<<dim3(SEQ / 256, NB_HEAD, BATCH), 512, 0, stream>>>(Qb, Kh, Vt, Mand, ctx);

  gemm_bt<2><<<ggrid, 256, 0, stream>>>(ctx, Wo_b, nullptr, out, hq, 1.0f);
}

// Round 9
// 241.790 us; speedup vs baseline: 1.7613x; 1.6474x over previous
//
#include <hip/hip_runtime.h>
#include <hip/hip_bf16.h>
#include <stdint.h>

typedef __bf16 bf16_t;
typedef bf16_t bf16x2 __attribute__((ext_vector_type(2)));
typedef bf16_t bf16x8 __attribute__((ext_vector_type(8)));
typedef float  f32x4  __attribute__((ext_vector_type(4)));
typedef float  f32x16 __attribute__((ext_vector_type(16)));
typedef unsigned uint2v __attribute__((ext_vector_type(2)));

#define NB_HEAD 16
#define DH      64
#define EMB     1024
#define BATCH   4
#define SEQ     2048
#define NTOK    (BATCH*SEQ)   // 8192

// scale * log2(e): folded into Q at projection time
#define QSCALE 0.1803368801111204f

// ---------------------------------------------------------------------------
// helpers
// ---------------------------------------------------------------------------
__device__ __forceinline__ void gload_lds16(const void* g, void* l) {
  __builtin_amdgcn_global_load_lds(
      (const __attribute__((address_space(1))) void*)g,
      (__attribute__((address_space(3))) void*)l, 16, 0, 0);
}

__device__ __forceinline__ uint32_t pkbf(float a, float b) {
  bf16x2 v = { (bf16_t)a, (bf16_t)b };     // fusable to v_cvt_pk_bf16_f32
  return __builtin_bit_cast(uint32_t, v);
}

__device__ __forceinline__ void cvt8_body(const float* __restrict__ in,
                                          bf16_t* __restrict__ out, int i) {
  const float4* p = reinterpret_cast<const float4*>(in) + (size_t)i * 2;
  float4 a = p[0], b = p[1];
  uint4 r;
  r.x = pkbf(a.x, a.y); r.y = pkbf(a.z, a.w);
  r.z = pkbf(b.x, b.y); r.w = pkbf(b.z, b.w);
  reinterpret_cast<uint4*>(out)[i] = r;
}

__device__ __forceinline__ void mkand_body(const uint8_t* __restrict__ m,
                                           uint16_t* __restrict__ out, int i) {
  uint2 v = reinterpret_cast<const uint2*>(m)[i];
  uint4 r;
  uint32_t lo = v.x, hi = v.y;
  uint16_t e[8];
#pragma unroll
  for (int j = 0; j < 4; j++) e[j]     = (uint16_t)(((lo >> (8 * j)) & 0xFF) - 1);
#pragma unroll
  for (int j = 0; j < 4; j++) e[4 + j] = (uint16_t)(((hi >> (8 * j)) & 0xFF) - 1);
  r.x = (uint32_t)e[0] | ((uint32_t)e[1] << 16);
  r.y = (uint32_t)e[2] | ((uint32_t)e[3] << 16);
  r.z = (uint32_t)e[4] | ((uint32_t)e[5] << 16);
  r.w = (uint32_t)e[6] | ((uint32_t)e[7] << 16);
  reinterpret_cast<uint4*>(out)[i] = r;
}

// ---------------------------------------------------------------------------
// prep: all f32->bf16 conversions (+ optional mask expansion) in ONE launch.
// ---------------------------------------------------------------------------
__global__ void __launch_bounds__(256)
prep(const float* __restrict__ hq, const float* __restrict__ hk,
     const float* __restrict__ hv, const float* __restrict__ Wq,
     const float* __restrict__ Wk, const float* __restrict__ Wv,
     const float* __restrict__ Wo,
     bf16_t* hq_b, bf16_t* hk_b, bf16_t* hv_b,
     bf16_t* Wq_b, bf16_t* Wk_b, bf16_t* Wv_b, bf16_t* Wo_b,
     const uint8_t* __restrict__ mask, uint16_t* __restrict__ mand) {
  const int bid = blockIdx.x;
  if (bid < 12288) {
    const int seg = bid >> 12;               // /4096
    const float* src = seg == 0 ? hq : seg == 1 ? hk : hv;
    bf16_t*      dst = seg == 0 ? hq_b : seg == 1 ? hk_b : hv_b;
    cvt8_body(src, dst, (bid & 4095) * 256 + (int)threadIdx.x);
  } else if (bid < 14336) {
    const int sb = bid - 12288;
    const int seg = sb >> 9;                 // /512
    const float* src = seg == 0 ? Wq : seg == 1 ? Wk : seg == 2 ? Wv : Wo;
    bf16_t*      dst = seg == 0 ? Wq_b : seg == 1 ? Wk_b : seg == 2 ? Wv_b : Wo_b;
    cvt8_body(src, dst, (sb & 511) * 256 + (int)threadIdx.x);
  } else {
    mkand_body(mask, mand, (bid - 14336) * 256 + (int)threadIdx.x);
  }
}

__global__ void __launch_bounds__(256)
mkand(const uint8_t* __restrict__ m, uint16_t* __restrict__ out) {
  mkand_body(m, out, blockIdx.x * 256 + (int)threadIdx.x);
}

// ---------------------------------------------------------------------------
// GEMM  C[M,N] = A[M,K] * Bw[N,K]^T, 128x128 tile, BK=64, double-buffered LDS
// (proven structure: stage at top, __syncthreads at bottom — race-free),
// XCD-swizzled block mapping. STABLE SINCE R4 — do not restructure.
// EPI 0: bf16 row-major, scaled by qscale  (Q) | EPI 1: Vt[b,h,d,s] (V)
// EPI 2: f32 + residual (out proj)             | EPI 3: Kh[b,h,s,d] (K)
// ---------------------------------------------------------------------------
#define BM 128
#define BN 128
#define BKT 64

template<int EPI>
__global__ void __launch_bounds__(256, 2)
gemm_bt(const bf16_t* __restrict__ A, const bf16_t* __restrict__ Bw,
        bf16_t* __restrict__ Cb, float* __restrict__ Cf,
        const float* __restrict__ resid, float qscale) {
  __shared__ bf16_t As[2][BM * BKT];
  __shared__ bf16_t Bs[2][BN * BKT];
  const int K = EMB, N = EMB;
  const int t    = threadIdx.x;
  const int lane = t & 63, w = t >> 6;
  const int wr = w >> 1, wc = w & 1;
  const int l15 = lane & 15, l4 = lane >> 4;

  // XCD swizzle: grid (8,64); give each XCD 8 contiguous row-stripes
  const int lin = blockIdx.x + 8 * blockIdx.y;
  const int nl  = (lin & 7) * 64 + (lin >> 3);
  const int rowBase = (nl >> 3) * BM, colBase = (nl & 7) * BN;

  f32x4 acc[4][4];
#pragma unroll
  for (int i = 0; i < 4; i++)
#pragma unroll
    for (int j = 0; j < 4; j++) acc[i][j] = f32x4{0.f, 0.f, 0.f, 0.f};

  const int lin16 = w * 1024 + lane * 16;

  // prologue: stage k0=0 into buf 0
#pragma unroll
  for (int i = 0; i < 4; ++i) {
    int off  = i * 4096 + lin16;
    int row  = off >> 7, colb = off & 127;
    gload_lds16((const char*)A  + (((size_t)(rowBase + row)) * K) * 2 + colb, (char*)As[0] + off);
    gload_lds16((const char*)Bw + (((size_t)(colBase + row)) * K) * 2 + colb, (char*)Bs[0] + off);
  }
  __syncthreads();

  int cur = 0;
  for (int k0 = 0; k0 < K; k0 += BKT) {
    if (k0 + BKT < K) {
      const int nb = cur ^ 1;
#pragma unroll
      for (int i = 0; i < 4; ++i) {
        int off  = i * 4096 + lin16;
        int row  = off >> 7, colb = off & 127;
        gload_lds16((const char*)A  + (((size_t)(rowBase + row)) * K + k0 + BKT) * 2 + colb, (char*)As[nb] + off);
        gload_lds16((const char*)Bw + (((size_t)(colBase + row)) * K + k0 + BKT) * 2 + colb, (char*)Bs[nb] + off);
      }
    }
#pragma unroll
    for (int kc = 0; kc < 2; ++kc) {
      bf16x8 af[4], bfb[4];
#pragma unroll
      for (int mi = 0; mi < 4; mi++)
        af[mi] = *reinterpret_cast<const bf16x8*>(
            &As[cur][(wr * 64 + mi * 16 + l15) * BKT + kc * 32 + l4 * 8]);
#pragma unroll
      for (int ni = 0; ni < 4; ni++)
        bfb[ni] = *reinterpret_cast<const bf16x8*>(
            &Bs[cur][(wc * 64 + ni * 16 + l15) * BKT + kc * 32 + l4 * 8]);
      __builtin_amdgcn_s_setprio(1);
#pragma unroll
      for (int mi = 0; mi < 4; mi++)
#pragma unroll
        for (int ni = 0; ni < 4; ni++)
          acc[mi][ni] = __builtin_amdgcn_mfma_f32_16x16x32_bf16(
              af[mi], bfb[ni], acc[mi][ni], 0, 0, 0);
      __builtin_amdgcn_s_setprio(0);
    }
    __syncthreads();   // drains vmcnt; protects both buffers (race-free)
    cur ^= 1;
  }

#pragma unroll
  for (int mi = 0; mi < 4; mi++) {
#pragma unroll
    for (int ni = 0; ni < 4; ni++) {
      const int m0 = rowBase + wr * 64 + mi * 16 + l4 * 4;
      const int n  = colBase + wc * 64 + ni * 16 + l15;
      if (EPI == 1) {
        size_t base = ((size_t)((m0 >> 11) * 1024 + n)) * 2048 + (m0 & 2047);
        uint2 st;
        st.x = pkbf(acc[mi][ni][0], acc[mi][ni][1]);
        st.y = pkbf(acc[mi][ni][2], acc[mi][ni][3]);
        *reinterpret_cast<uint2*>(Cb + base) = st;
      } else {
#pragma unroll
        for (int r = 0; r < 4; r++) {
          int m = m0 + r;
          float v = acc[mi][ni][r];
          if (EPI == 0) {
            Cb[(size_t)m * N + n] = (bf16_t)(v * qscale);
          } else if (EPI == 3) {
            Cb[(((size_t)((m >> 11) * 16 + (n >> 6))) * 2048 + (m & 2047)) * 64 + (n & 63)] = (bf16_t)v;
          } else {
            Cf[(size_t)m * N + n] = v + resid[(size_t)m * N + n];
          }
        }
      }
    }
  }
}

// ---------------------------------------------------------------------------
// Flash attention — EXACT restore of the Round-4-result kernel (115.4 us,
// FETCH 63 MB, WRITE 16 MB, VGPR 60, no scratch). Swapped-operand 32x32x16,
// POST-softmax masking, no online max (Q pre-scaled; P = exp2(acc)),
// VALU ps denominator. KVBLK=64, 512 thr = 8 waves x 32 q-rows.
// *** DO NOT restructure this inner loop: KVB=128 variants and mask-hoisting
// *** variants (R5-R8) all triggered scratch spills (~0.5 GB r/w, 2.3x slower).
// ---------------------------------------------------------------------------
__global__ void __launch_bounds__(512, 2)
attn32(const bf16_t* __restrict__ Qb, const bf16_t* __restrict__ Kh,
       const bf16_t* __restrict__ Vt, const uint16_t* __restrict__ Mand,
       bf16_t* __restrict__ ctx) {
  __shared__ __align__(16) bf16_t Ks[2][64 * 64];
  __shared__ __align__(16) bf16_t Vs[2][64 * 64];

  const int t = threadIdx.x, lane = t & 63, wid = t >> 6;
  const int q = lane & 31, hi = lane >> 5;

  // XCD swizzle: 512 blocks; mask/K/V sharers land on the same XCD
  const int lin = blockIdx.x + 8 * (blockIdx.y + 16 * blockIdx.z);
  const int nl  = (lin & 7) * 64 + (lin >> 3);
  const int bx = nl & 7, h = (nl >> 3) & 15, b = nl >> 7;

  const int q0 = bx * 256 + wid * 32;
  const int qrow = b * SEQ + q0 + q;

  // staging geometry: 512 thr x 16B = 8KB = one full 64-row tile per issue
  const int srow  = t >> 3;                            // 0..63
  const int scolx = ((t & 7) ^ ((t >> 3) & 7)) * 16;   // pre-swizzled source col
  const char* kg = (const char*)(Kh + ((size_t)(b * NB_HEAD + h)) * SEQ * DH);
  const char* vg = (const char*)(Vt + ((size_t)(b * NB_HEAD + h)) * DH * SEQ);

  // Q fragments (B operand): lane -> row q, k-halves hi*8 (pre-scaled)
  const bf16_t* qp = Qb + (size_t)qrow * EMB + h * DH + hi * 8;
  bf16x8 qf[4];
#pragma unroll
  for (int d = 0; d < 4; d++) qf[d] = *reinterpret_cast<const bf16x8*>(qp + d * 16);

  f32x16 o0 = {0}, o1 = {0};
  float lrun = 0.f;
  const uint16_t* mbase = Mand + (size_t)qrow * SEQ;
  const int qx = (q & 7) << 4;   // swizzled read col base (q and q+32 share q&7)

  // prologue: stage tile 0 into buf 0
  gload_lds16(kg + (size_t)srow * 128 + scolx,  (char*)Ks[0] + t * 16);
  gload_lds16(vg + (size_t)srow * 4096 + scolx, (char*)Vs[0] + t * 16);
  __syncthreads();

  int cur = 0;
  for (int kb = 0; kb < SEQ; kb += 64) {
    // issue next tile's staging (overlaps with this tile's compute)
    if (kb + 64 < SEQ) {
      const int nb = cur ^ 1;
      gload_lds16(kg + (size_t)(kb + 64) * 128 + (size_t)srow * 128 + scolx,
                  (char*)Ks[nb] + t * 16);
      gload_lds16(vg + (size_t)(kb + 64) * 2 + (size_t)srow * 4096 + scolx,
                  (char*)Vs[nb] + t * 16);
    }

    // ---- QK^T (swapped) from LDS: p holds log2-domain scores ----
    const char* kls = (const char*)Ks[cur];
    f32x16 p0 = {0}, p1 = {0};
    __builtin_amdgcn_s_setprio(1);
#pragma unroll
    for (int dsl = 0; dsl < 4; dsl++) {
      const int cb = (dsl * 32 + hi * 16) ^ qx;
      bf16x8 kf0 = *reinterpret_cast<const bf16x8*>(kls + q * 128 + cb);
      bf16x8 kf1 = *reinterpret_cast<const bf16x8*>(kls + (32 + q) * 128 + cb);
      p0 = __builtin_amdgcn_mfma_f32_32x32x16_bf16(kf0, qf[dsl], p0, 0, 0, 0);
      p1 = __builtin_amdgcn_mfma_f32_32x32x16_bf16(kf1, qf[dsl], p1, 0, 0, 0);
    }
    __builtin_amdgcn_s_setprio(0);

    // ---- mask loads (latency hidden under exp) ----
    uint4 mv[4];
#pragma unroll
    for (int ks = 0; ks < 4; ks++)
      mv[ks] = *reinterpret_cast<const uint4*>(mbase + kb + 16 * ks + 8 * hi);

    // ---- exp2, unmasked denominator ----
    float ps = 0.f;
#pragma unroll
    for (int i = 0; i < 16; i++) { p0[i] = __builtin_amdgcn_exp2f(p0[i]); ps += p0[i]; }
#pragma unroll
    for (int i = 0; i < 16; i++) { p1[i] = __builtin_amdgcn_exp2f(p1[i]); ps += p1[i]; }
    ps += __shfl_xor(ps, 32);
    lrun += ps;

    // ---- build PA fragments (permlane32_swap), mask, PV ----
    const char* vls = (const char*)Vs[cur];
#pragma unroll
    for (int ks = 0; ks < 4; ks++) {
      const int s8 = (ks & 1) * 8;
      float e0, e1, e2, e3, e4, e5, e6, e7;
      if (ks < 2) {
        e0 = p0[s8+0]; e1 = p0[s8+1]; e2 = p0[s8+2]; e3 = p0[s8+3];
        e4 = p0[s8+4]; e5 = p0[s8+5]; e6 = p0[s8+6]; e7 = p0[s8+7];
      } else {
        e0 = p1[s8+0]; e1 = p1[s8+1]; e2 = p1[s8+2]; e3 = p1[s8+3];
        e4 = p1[s8+4]; e5 = p1[s8+5]; e6 = p1[s8+6]; e7 = p1[s8+7];
      }
      uint32_t a0 = pkbf(e0, e1), a1 = pkbf(e2, e3);
      uint32_t a2 = pkbf(e4, e5), a3 = pkbf(e6, e7);
      uint2v s02 = __builtin_amdgcn_permlane32_swap(a0, a2, false, false);
      uint2v s13 = __builtin_amdgcn_permlane32_swap(a1, a3, false, false);
      uint4 fr;
      fr.x = s02[0]; fr.y = s13[0]; fr.z = s02[1]; fr.w = s13[1];
      fr.x &= mv[ks].x; fr.y &= mv[ks].y; fr.z &= mv[ks].z; fr.w &= mv[ks].w;
      bf16x8 pa = __builtin_bit_cast(bf16x8, fr);
      const int cb = (ks * 32 + hi * 16) ^ qx;
      bf16x8 vf0 = *reinterpret_cast<const bf16x8*>(vls + q * 128 + cb);
      bf16x8 vf1 = *reinterpret_cast<const bf16x8*>(vls + (32 + q) * 128 + cb);
      __builtin_amdgcn_s_setprio(1);
      o0 = __builtin_amdgcn_mfma_f32_32x32x16_bf16(vf0, pa, o0, 0, 0, 0);
      o1 = __builtin_amdgcn_mfma_f32_32x32x16_bf16(vf1, pa, o1, 0, 0, 0);
      __builtin_amdgcn_s_setprio(0);
    }

    __syncthreads();
    cur ^= 1;
  }

  // ---- epilogue ----
  float inv = 1.0f / lrun;
  bf16_t* cp = ctx + (size_t)qrow * EMB + h * DH;
#pragma unroll
  for (int g = 0; g < 4; g++) {
    uint2 st;
    st.x = pkbf(o0[4*g+0] * inv, o0[4*g+1] * inv);
    st.y = pkbf(o0[4*g+2] * inv, o0[4*g+3] * inv);
    *reinterpret_cast<uint2*>(cp + 8 * g + 4 * hi) = st;
    st.x = pkbf(o1[4*g+0] * inv, o1[4*g+1] * inv);
    st.y = pkbf(o1[4*g+2] * inv, o1[4*g+3] * inv);
    *reinterpret_cast<uint2*>(cp + 32 + 8 * g + 4 * hi) = st;
  }
}

// ---------------------------------------------------------------------------
// launcher
// ---------------------------------------------------------------------------
extern "C" void kernel_launch(void* const* d_in, const int* in_sizes, int n_in,
                              void* d_out, int out_size, void* d_ws, size_t ws_size,
                              hipStream_t stream) {
  const float*   hq   = (const float*)d_in[0];
  const float*   hk   = (const float*)d_in[1];
  const float*   hv   = (const float*)d_in[2];
  const uint8_t* mask = (const uint8_t*)d_in[3];
  const float*   Wq   = (const float*)d_in[4];
  const float*   Wk   = (const float*)d_in[5];
  const float*   Wv   = (const float*)d_in[6];
  const float*   Wo   = (const float*)d_in[7];
  float* out = (float*)d_out;

  char* ws = (char*)d_ws;
  const size_t SZ_H = (size_t)NTOK * EMB * 2;        // 16 MiB
  const size_t SZ_W = (size_t)EMB * EMB * 2;         // 2 MiB
  bf16_t* hq_b = (bf16_t*)(ws + 0 * SZ_H);
  bf16_t* hk_b = (bf16_t*)(ws + 1 * SZ_H);
  bf16_t* hv_b = (bf16_t*)(ws + 2 * SZ_H);
  bf16_t* Qb   = (bf16_t*)(ws + 3 * SZ_H);
  bf16_t* Kh   = (bf16_t*)(ws + 4 * SZ_H);
  bf16_t* Vt   = (bf16_t*)(ws + 5 * SZ_H);
  bf16_t* ctx  = (bf16_t*)(ws + 6 * SZ_H);
  bf16_t* Wq_b = (bf16_t*)(ws + 7 * SZ_H + 0 * SZ_W);
  bf16_t* Wk_b = (bf16_t*)(ws + 7 * SZ_H + 1 * SZ_W);
  bf16_t* Wv_b = (bf16_t*)(ws + 7 * SZ_H + 2 * SZ_W);
  bf16_t* Wo_b = (bf16_t*)(ws + 7 * SZ_H + 3 * SZ_W);

  const size_t MAND_OFF = 7 * SZ_H + 4 * SZ_W;                 // 120 MiB
  const size_t MAND_SZ  = (size_t)BATCH * SEQ * SEQ * 2;       // 32 MiB
  const bool bigws = ws_size >= MAND_OFF + MAND_SZ;
  // fallback: Mand aliases hq_b/hk_b/hv_b (dead after the QKV gemms)
  uint16_t* Mand = bigws ? (uint16_t*)(ws + MAND_OFF) : (uint16_t*)ws;

  prep<<<bigws ? 22528 : 14336, 256, 0, stream>>>(
      hq, hk, hv, Wq, Wk, Wv, Wo,
      hq_b, hk_b, hv_b, Wq_b, Wk_b, Wv_b, Wo_b, mask, Mand);

  dim3 ggrid(EMB / BN, NTOK / BM);  // (8, 64)
  gemm_bt<0><<<ggrid, 256, 0, stream>>>(hq_b, Wq_b, Qb, nullptr, nullptr, QSCALE);
  gemm_bt<3><<<ggrid, 256, 0, stream>>>(hk_b, Wk_b, Kh, nullptr, nullptr, 1.0f);
  gemm_bt<1><<<ggrid, 256, 0, stream>>>(hv_b, Wv_b, Vt, nullptr, nullptr, 1.0f);

  if (!bigws) mkand<<<8192, 256, 0, stream>>>(mask, Mand);

  attn32<<<dim3(SEQ / 256, NB_HEAD, BATCH), 512, 0, stream>>>(Qb, Kh, Vt, Mand, ctx);

  gemm_bt<2><<<ggrid, 256, 0, stream>>>(ctx, Wo_b, nullptr, out, hq, 1.0f);
}